// Round 11
// baseline (215.602 us; speedup 1.0000x reference)
//
#include <hip/hip_runtime.h>
#include <hip/hip_bf16.h>

#define IN_FEATS 602
#define N_HIDDEN 256
#define N_CLASSES 41
#define N_SRC0 292864
#define N_DST0 11264
#define N_DST1 1024
#define FAN0 25
#define FAN1 10
#define KPAD 1216            // 1204 rounded up to multiple of 64
#define NWP ((KPAD / 32) * (N_HIDDEN / 32))   // 304 wprep blocks
#define NAGGB 1024           // agg blocks: exactly co-resident (4 blk/CU x 256 CU)
#define NWAVE (NAGGB * 4)    // 4096 gather waves
#define NWIN 4
#define WINSZ (N_SRC0 / NWIN)   // 73216 rows = 176 MB < 256 MB L3

typedef __attribute__((ext_vector_type(4))) float f32x4;
typedef __attribute__((ext_vector_type(8))) short bf16x8;   // 8 bf16 = 4 VGPRs

// round-to-nearest-even f32 -> bf16, packed pair
static __device__ __forceinline__ unsigned pack_bf16x2(float lo, float hi) {
    unsigned a = __float_as_uint(lo);
    unsigned b = __float_as_uint(hi);
    a = (a + 0x7fffu + ((a >> 16) & 1u)) >> 16;
    b = (b + 0x7fffu + ((b >> 16) & 1u)) >> 16;
    return (a & 0xffffu) | (b << 16);
}

// ---------------------------------------------------------------------------
// Kernel 1 (combo):
//  blocks [0,NWP): W transpose (R2-verified body).
//  blocks [NWP, NWP+NAGGB): WINDOWED gather. Each wave owns 2-3 dsts with
//  persistent accumulators; indices sorted per dst (R9-verified rank sort);
//  all waves process window w (rows [w*WINSZ,(w+1)*WINSZ)) before w+1.
//  Grid is exactly co-resident -> machine-wide instantaneous read footprint
//  is hard-capped at 176 MB (L3-sized): duplicate row reads hit L3.
// ---------------------------------------------------------------------------
__global__ __launch_bounds__(256, 4) void prep_kernel(
    const float* __restrict__ x,
    const int* __restrict__ idx,
    const float* __restrict__ Ws,
    const float* __restrict__ Wn,
    __hip_bfloat16* __restrict__ A,
    __hip_bfloat16* __restrict__ Wt)
{
    __shared__ __align__(16) char sm[4356];

    if (blockIdx.x < NWP) {
        // ---- wprep role ----
        float (*tile)[33] = (float(*)[33])sm;
        const int b = blockIdx.x;
        const int k0 = (b % (KPAD / 32)) * 32;
        const int n0 = (b / (KPAD / 32)) * 32;
        const int tx = threadIdx.x & 31, ty = threadIdx.x >> 5;   // 32 x 8

        #pragma unroll
        for (int i = 0; i < 4; ++i) {
            const int k = k0 + ty + i * 8;
            const int n = n0 + tx;
            float v = 0.f;
            if (k < IN_FEATS)            v = Ws[(size_t)k * N_HIDDEN + n];
            else if (k < 2 * IN_FEATS)   v = Wn[(size_t)(k - IN_FEATS) * N_HIDDEN + n];
            tile[ty + i * 8][tx] = v;
        }
        __syncthreads();
        #pragma unroll
        for (int i = 0; i < 4; ++i) {
            const int n = n0 + ty + i * 8;
            const int k = k0 + tx;
            Wt[(size_t)n * KPAD + k] = __float2bfloat16(tile[tx][ty + i * 8]);
        }
        return;
    }

    // ---- agg role: windowed gather ----
    const int b    = blockIdx.x - NWP;        // 0..1023
    const int wave = threadIdx.x >> 6;
    const int lane = threadIdx.x & 63;
    const int wid  = b * 4 + wave;            // 0..4095
    // wid < 3072 -> 3 dsts, else 2. (3072 % 4 == 0 -> dcnt uniform per block)
    const int dcnt = (wid < N_DST0 - 2 * NWAVE) ? 3 : 2;
    const int dstA[3] = { wid, wid + NWAVE, wid + 2 * NWAVE };

    int (*srt)[3][FAN0] = (int(*)[3][FAN0])sm;          // [4][3][25]
    int (*raw)[FAN0]    = (int(*)[FAN0])(sm + 1216);    // [4][25]

    // sort each dst's 25 indices ascending (rank sort, R9-verified)
    #pragma unroll
    for (int d = 0; d < 3; ++d) {
        if (d < dcnt && lane < FAN0)
            raw[wave][lane] = idx[dstA[d] * FAN0 + lane];
        __syncthreads();
        if (d < dcnt && lane < FAN0) {
            const int v = raw[wave][lane];
            int rank = 0;
            #pragma unroll
            for (int j = 0; j < FAN0; ++j) {
                const int u = raw[wave][j];
                rank += (u < v) || (u == v && j < lane);
            }
            srt[wave][d][rank] = v;
        }
        __syncthreads();
    }

    float accx[3][5], accy[3][5];
    #pragma unroll
    for (int d = 0; d < 3; ++d)
        #pragma unroll
        for (int c = 0; c < 5; ++c) { accx[d][c] = 0.f; accy[d][c] = 0.f; }

    int c0 = 0, c1 = 0, c2 = 0;   // named cursors (static acc indexing, rule #20)

#define GATHER_D(D, CUR) \
    while (CUR < FAN0) { \
        const int ri = srt[wave][D][CUR]; \
        if (ri >= hi) break; \
        const float* xr = x + (size_t)ri * IN_FEATS; \
        _Pragma("unroll") \
        for (int c = 0; c < 5; ++c) { \
            const int f = c * 128 + lane * 2; \
            if (f < IN_FEATS) { \
                const float2 v = *(const float2*)&xr[f]; \
                accx[D][c] += v.x; accy[D][c] += v.y; \
            } \
        } \
        ++CUR; \
    }

    #pragma unroll 1
    for (int w = 0; w < NWIN; ++w) {
        const int hi = (w + 1) * WINSZ;
        GATHER_D(0, c0)
        GATHER_D(1, c1)
        if (dcnt == 3) { GATHER_D(2, c2) }
        __syncthreads();   // phase-lock the block's 4 waves per window
    }
#undef GATHER_D

    // epilogue: self row + pack + write (R10-verified body, per dst)
    #pragma unroll
    for (int d = 0; d < 3; ++d) {
        if (d >= dcnt) break;
        const int dd = dstA[d];
        unsigned* Arow = (unsigned*)(A + (size_t)dd * KPAD);
        const float* xself = x + (size_t)dd * IN_FEATS;
        if (lane < 6) Arow[602 + lane] = 0u;   // zero pad cols 1204..1215
        #pragma unroll
        for (int c = 0; c < 5; ++c) {
            const int f = c * 128 + lane * 2;
            if (f < IN_FEATS) {
                const int f2 = f >> 1;
                const float2 sv = *(const float2*)&xself[f];
                Arow[f2] = pack_bf16x2(sv.x, sv.y);
                *(unsigned*)((char*)Arow + 1204 + f2 * 4) =
                    pack_bf16x2(accx[d][c] * (1.0f / FAN0), accy[d][c] * (1.0f / FAN0));
            }
        }
    }
}

// ---------------------------------------------------------------------------
// Kernel 2: h = relu(A @ Wt^T + b0). R10-verified: 64x64 tile, BK=64,
// double-buffered single-barrier loop, XCD-swizzled block id.
// ---------------------------------------------------------------------------
#define BKK 64
#define LDSW 72

__global__ __launch_bounds__(256) void gemm0_mfma(
    const __hip_bfloat16* __restrict__ A,     // [N_DST0][KPAD]
    const __hip_bfloat16* __restrict__ Wt,    // [N_HIDDEN][KPAD]
    const float* __restrict__ bias,           // [256]
    float* __restrict__ h)                    // [N_DST0][256]
{
    __shared__ __hip_bfloat16 As[2][64 * LDSW];
    __shared__ __hip_bfloat16 Bs[2][64 * LDSW];

    // de-swizzle: D = s + 8*(bx + 4*q), by = 8*q + s  (bijective, 704 blocks)
    const int D = blockIdx.x;
    const int s = D & 7;
    const int e = D >> 3;
    const int bx = e & 3;
    const int by = 8 * (e >> 2) + s;

    const int tid  = threadIdx.x;
    const int lane = tid & 63;
    const int wave = tid >> 6;
    const int wm = wave >> 1, wn = wave & 1;    // 2x2 waves of 32x32
    const int g = lane >> 4, r = lane & 15;
    const int m0 = by * 64, n0 = bx * 64;

    const int srow = tid >> 2;
    const int sc   = (tid & 3) * 16;
    const int sbase = srow * LDSW + sc;

    const size_t a_off = (size_t)(m0 + srow) * KPAD + sc;
    const size_t b_off = (size_t)(n0 + srow) * KPAD + sc;

    f32x4 acc[2][2] = {};

    float4 ra0, ra1, rb0, rb1;
    ra0 = *(const float4*)&A[a_off];      ra1 = *(const float4*)&A[a_off + 8];
    rb0 = *(const float4*)&Wt[b_off];     rb1 = *(const float4*)&Wt[b_off + 8];
    *(float4*)&As[0][sbase] = ra0;  *(float4*)&As[0][sbase + 8] = ra1;
    *(float4*)&Bs[0][sbase] = rb0;  *(float4*)&Bs[0][sbase + 8] = rb1;

    const int NT = KPAD / BKK;   // 19
    for (int t = 0; t < NT; ++t) {
        __syncthreads();
        const int cur = t & 1;

        if (t + 1 < NT) {
            const size_t k1 = (size_t)(t + 1) * BKK;
            ra0 = *(const float4*)&A[a_off + k1];      ra1 = *(const float4*)&A[a_off + k1 + 8];
            rb0 = *(const float4*)&Wt[b_off + k1];     rb1 = *(const float4*)&Wt[b_off + k1 + 8];
        }

        #pragma unroll
        for (int kh = 0; kh < 2; ++kh) {
            const bf16x8 af0 = *(const bf16x8*)&As[cur][(wm * 32 +      r) * LDSW + kh * 32 + g * 8];
            const bf16x8 af1 = *(const bf16x8*)&As[cur][(wm * 32 + 16 + r) * LDSW + kh * 32 + g * 8];
            const bf16x8 bf0 = *(const bf16x8*)&Bs[cur][(wn * 32 +      r) * LDSW + kh * 32 + g * 8];
            const bf16x8 bf1 = *(const bf16x8*)&Bs[cur][(wn * 32 + 16 + r) * LDSW + kh * 32 + g * 8];

            acc[0][0] = __builtin_amdgcn_mfma_f32_16x16x32_bf16(af0, bf0, acc[0][0], 0, 0, 0);
            acc[0][1] = __builtin_amdgcn_mfma_f32_16x16x32_bf16(af0, bf1, acc[0][1], 0, 0, 0);
            acc[1][0] = __builtin_amdgcn_mfma_f32_16x16x32_bf16(af1, bf0, acc[1][0], 0, 0, 0);
            acc[1][1] = __builtin_amdgcn_mfma_f32_16x16x32_bf16(af1, bf1, acc[1][1], 0, 0, 0);
        }

        if (t + 1 < NT) {
            const int nxt = cur ^ 1;
            *(float4*)&As[nxt][sbase] = ra0;  *(float4*)&As[nxt][sbase + 8] = ra1;
            *(float4*)&Bs[nxt][sbase] = rb0;  *(float4*)&Bs[nxt][sbase + 8] = rb1;
        }
    }

    // C/D layout (m89-verified): col = lane&15, row = (lane>>4)*4 + j
    #pragma unroll
    for (int mh = 0; mh < 2; ++mh)
        #pragma unroll
        for (int nh = 0; nh < 2; ++nh) {
            const int col = n0 + wn * 32 + nh * 16 + r;
            const float bv = bias[col];
            #pragma unroll
            for (int j = 0; j < 4; ++j) {
                const int row = m0 + wm * 32 + mh * 16 + g * 4 + j;
                const float v = acc[mh][nh][j] + bv;
                h[(size_t)row * N_HIDDEN + col] = fmaxf(v, 0.f);
            }
        }
}

// ---------------------------------------------------------------------------
// Kernel 3: out[d] = h[d]@Ws1 + (mean_10 h[idx1])@Wn1 + b1.  4 dsts/block.
// (verified R5)
// ---------------------------------------------------------------------------
__global__ __launch_bounds__(256) void tail_kernel(
    const float* __restrict__ h,
    const int* __restrict__ idx1,
    const float* __restrict__ Ws,     // [256][41]
    const float* __restrict__ Wn,     // [256][41]
    const float* __restrict__ b,      // [41]
    float* __restrict__ out)          // [1024][41]
{
    const int w = threadIdx.x >> 6;
    const int lane = threadIdx.x & 63;
    const int d = blockIdx.x * 4 + w;

    __shared__ float hd[4][N_HIDDEN];
    __shared__ float hn[4][N_HIDDEN];
    __shared__ int sidx[4][FAN1];
    if (lane < FAN1) sidx[w][lane] = idx1[d * FAN1 + lane];
    __syncthreads();

    {
        const int k0 = lane * 4;
        const float4 self = *(const float4*)&h[(size_t)d * N_HIDDEN + k0];
        float ax = 0.f, ay = 0.f, az = 0.f, aw = 0.f;
        #pragma unroll
        for (int i = 0; i < FAN1; ++i) {
            const float4 v = *(const float4*)&h[(size_t)sidx[w][i] * N_HIDDEN + k0];
            ax += v.x; ay += v.y; az += v.z; aw += v.w;
        }
        *(float4*)&hd[w][k0] = self;
        hn[w][k0 + 0] = ax * (1.0f / FAN1);
        hn[w][k0 + 1] = ay * (1.0f / FAN1);
        hn[w][k0 + 2] = az * (1.0f / FAN1);
        hn[w][k0 + 3] = aw * (1.0f / FAN1);
    }
    __syncthreads();

    if (lane < N_CLASSES) {
        const int n = lane;
        float a0 = b[n], a1 = 0.f, a2 = 0.f, a3 = 0.f;
        #pragma unroll 4
        for (int k = 0; k < N_HIDDEN; k += 4) {
            a0 += hd[w][k + 0] * Ws[(k + 0) * N_CLASSES + n] + hn[w][k + 0] * Wn[(k + 0) * N_CLASSES + n];
            a1 += hd[w][k + 1] * Ws[(k + 1) * N_CLASSES + n] + hn[w][k + 1] * Wn[(k + 1) * N_CLASSES + n];
            a2 += hd[w][k + 2] * Ws[(k + 2) * N_CLASSES + n] + hn[w][k + 2] * Wn[(k + 2) * N_CLASSES + n];
            a3 += hd[w][k + 3] * Ws[(k + 3) * N_CLASSES + n] + hn[w][k + 3] * Wn[(k + 3) * N_CLASSES + n];
        }
        out[(size_t)d * N_CLASSES + n] = a0 + a1 + a2 + a3;
    }
}

// ---------------------------------------------------------------------------
extern "C" void kernel_launch(void* const* d_in, const int* in_sizes, int n_in,
                              void* d_out, int out_size, void* d_ws, size_t ws_size,
                              hipStream_t stream) {
    const float* x       = (const float*)d_in[0];
    const float* Wself0  = (const float*)d_in[1];
    const float* Wneigh0 = (const float*)d_in[2];
    const float* b0      = (const float*)d_in[3];
    const float* Wself1  = (const float*)d_in[4];
    const float* Wneigh1 = (const float*)d_in[5];
    const float* b1      = (const float*)d_in[6];
    const int*   idx0    = (const int*)d_in[7];
    const int*   idx1    = (const int*)d_in[8];
    float* out = (float*)d_out;

    // ws layout: A bf16 [11264*1216] | Wt bf16 [256*1216] | h f32 [11264*256]
    __hip_bfloat16* Abf = (__hip_bfloat16*)d_ws;
    __hip_bfloat16* Wt  = Abf + (size_t)N_DST0 * KPAD;
    float*          h   = (float*)(Wt + (size_t)N_HIDDEN * KPAD);

    prep_kernel<<<NWP + NAGGB, 256, 0, stream>>>(x, idx0, Wself0, Wneigh0, Abf, Wt);
    gemm0_mfma<<<(N_HIDDEN / 64) * (N_DST0 / 64), 256, 0, stream>>>(Abf, Wt, b0, h);
    tail_kernel<<<N_DST1 / 4, 256, 0, stream>>>(h, idx1, Wself1, Wneigh1, b1, out);
}